// Round 4
// baseline (154.930 us; speedup 1.0000x reference)
//
#include <hip/hip_runtime.h>

#define VV 4
#define NN 4096
#define HH 128
#define CAP 64
#define R2 16      // rows per block in fused layer2
#define FR 16      // rows per block in fusion
#define CHP (NN / R2)   // 256 column-sum partial chunks per view

typedef __attribute__((ext_vector_type(4))) float fvec4;   // nontemporal-loadable

// ---------------------------------------------------------------------------
// Kernel 1: scan dense adjacency -> per-row neighbor lists + dinv.
// 1 wave per row, 4 rows per 256-thread block. Nontemporal float4 loads.
// ---------------------------------------------------------------------------
__global__ __launch_bounds__(256) void k_build_csr(
    const float* __restrict__ adjs, int* __restrict__ nbr,
    int* __restrict__ cnt, float* __restrict__ dinv)
{
    int wave = threadIdx.x >> 6;
    int lane = threadIdx.x & 63;
    int r = blockIdx.x * 4 + wave;              // global row in [0, V*N)
    const fvec4* row = (const fvec4*)(adjs + (size_t)r * NN);
    int* out = nbr + (size_t)r * CAP;
    unsigned long long lm = (1ull << lane) - 1ull;
    int base = 0;
    #pragma unroll 4
    for (int c = 0; c < NN / 256; ++c) {
        fvec4 x = __builtin_nontemporal_load(&row[c * 64 + lane]);
        int c0 = (x.x != 0.f), c1 = (x.y != 0.f), c2 = (x.z != 0.f), c3 = (x.w != 0.f);
        unsigned long long b0 = __ballot(c0), b1 = __ballot(c1);
        unsigned long long b2 = __ballot(c2), b3 = __ballot(c3);
        int pos = base + __popcll(b0 & lm) + __popcll(b1 & lm)
                       + __popcll(b2 & lm) + __popcll(b3 & lm);
        int e = c * 256 + lane * 4;
        if (c0 && pos < CAP) out[pos] = e;     pos += c0;
        if (c1 && pos < CAP) out[pos] = e + 1; pos += c1;
        if (c2 && pos < CAP) out[pos] = e + 2; pos += c2;
        if (c3 && pos < CAP) out[pos] = e + 3; pos += c3;
        base += __popcll(b0) + __popcll(b1) + __popcll(b2) + __popcll(b3);
    }
    if (lane == 0) {
        cnt[r]  = base < CAP ? base : CAP;
        dinv[r] = rsqrtf((float)(base + 1));   // +1 self loop
    }
}

// ---------------------------------------------------------------------------
// Kernel 2: h1 = relu(A_norm @ w1 + b1).  4 rows per 512-thread block.
// ---------------------------------------------------------------------------
__global__ __launch_bounds__(512) void k_spmm1(
    const float* __restrict__ w1, const float* __restrict__ b1,
    const int* __restrict__ nbr, const int* __restrict__ cnt,
    const float* __restrict__ dinv, float* __restrict__ h1)
{
    int g = threadIdx.x >> 7;           // row group 0..3
    int h = threadIdx.x & 127;
    int r = blockIdx.x * 4 + g;         // [0, V*N)
    int v = r >> 12;
    __shared__ int   s_j[4][CAP];
    __shared__ float s_w[4][CAP];
    int n = cnt[r];
    float dr = dinv[r];
    if (h < n) {
        int j = nbr[(size_t)r * CAP + h];
        s_j[g][h] = j;
        s_w[g][h] = dinv[v * NN + j];
    }
    __syncthreads();
    float acc = dr * w1[(size_t)r * HH + h];            // self loop term
    #pragma unroll 4
    for (int k = 0; k < n; ++k)
        acc += s_w[g][k] * w1[((size_t)(v * NN + s_j[g][k])) * HH + h];
    float val = dr * acc + b1[v * HH + h];
    h1[(size_t)r * HH + h] = val > 0.f ? val : 0.f;
}

// ---------------------------------------------------------------------------
// Kernel 3 (fused layer 2): per 16-row block
//   u = A_norm @ h1  (gather, staged in LDS)
//   h2 = relu(u @ w2 + b2)      (register-tiled 2x4)
//   + per-block column partial sums of h2 (for attention summaries)
// Uses (A_norm h1) w2 == A_norm (h1 w2)  [both linear].
// ---------------------------------------------------------------------------
__global__ __launch_bounds__(256) void k_layer2(
    const float* __restrict__ h1, const float* __restrict__ w2,
    const float* __restrict__ b2, const int* __restrict__ nbr,
    const int* __restrict__ cnt, const float* __restrict__ dinv,
    float* __restrict__ h2, float* __restrict__ part)
{
    const int bpv = NN / R2;            // 256
    int v = blockIdx.x / bpv;
    int gr0 = blockIdx.x * R2;          // first global row of this block
    __shared__ int   s_n[R2];
    __shared__ float s_dr[R2];
    __shared__ int   s_j[R2][CAP];
    __shared__ float s_w[R2][CAP];
    __shared__ float s_u[R2][HH];
    __shared__ float s_p[8][HH];

    if (threadIdx.x < R2) {
        s_n[threadIdx.x]  = cnt[gr0 + threadIdx.x];
        s_dr[threadIdx.x] = dinv[gr0 + threadIdx.x];
    }
    __syncthreads();
    for (int idx = threadIdx.x; idx < R2 * CAP; idx += 256) {
        int rr = idx >> 6, kk = idx & 63;
        if (kk < s_n[rr]) {
            int j = nbr[(size_t)(gr0 + rr) * CAP + kk];
            s_j[rr][kk] = j;
            s_w[rr][kk] = dinv[v * NN + j];
        }
    }
    __syncthreads();

    // gather phase: 16 threads per row, 8 h-values each
    {
        int rr  = threadIdx.x >> 4;         // 0..15
        int t16 = threadIdx.x & 15;
        int h0  = t16 * 8;
        int n   = s_n[rr];
        float dr = s_dr[rr];
        const float* self = h1 + (size_t)(gr0 + rr) * HH + h0;
        float a[8];
        #pragma unroll
        for (int q = 0; q < 8; ++q) a[q] = dr * self[q];
        #pragma unroll 2
        for (int k = 0; k < n; ++k) {
            float wj = s_w[rr][k];
            const float4* src = (const float4*)(h1 + ((size_t)(v * NN + s_j[rr][k])) * HH + h0);
            float4 x0 = src[0], x1 = src[1];
            a[0] += wj * x0.x; a[1] += wj * x0.y; a[2] += wj * x0.z; a[3] += wj * x0.w;
            a[4] += wj * x1.x; a[5] += wj * x1.y; a[6] += wj * x1.z; a[7] += wj * x1.w;
        }
        #pragma unroll
        for (int q = 0; q < 8; ++q) s_u[rr][h0 + q] = dr * a[q];
    }
    __syncthreads();

    // GEMM phase: h2_blk[16][128] = relu(s_u @ w2v + b2), 2x4 per thread
    int r0 = (threadIdx.x >> 5) * 2;        // 0..14
    int c0 = (threadIdx.x & 31) * 4;        // 0..124
    const float* wv = w2 + (size_t)v * HH * HH;
    float acc[2][4];
    #pragma unroll
    for (int i = 0; i < 2; ++i)
        #pragma unroll
        for (int j = 0; j < 4; ++j) acc[i][j] = 0.f;
    for (int k = 0; k < HH; k += 4) {
        float4 a[2], w[4];
        #pragma unroll
        for (int i = 0; i < 2; ++i) a[i] = *(const float4*)&s_u[r0 + i][k];
        #pragma unroll
        for (int kk = 0; kk < 4; ++kk) w[kk] = *(const float4*)&wv[(size_t)(k + kk) * HH + c0];
        #pragma unroll
        for (int i = 0; i < 2; ++i)
            #pragma unroll
            for (int j = 0; j < 4; ++j) {
                acc[i][j] += a[i].x * ((const float*)&w[0])[j];
                acc[i][j] += a[i].y * ((const float*)&w[1])[j];
                acc[i][j] += a[i].z * ((const float*)&w[2])[j];
                acc[i][j] += a[i].w * ((const float*)&w[3])[j];
            }
    }
    float p[4];
    #pragma unroll
    for (int j = 0; j < 4; ++j) {
        float b = b2[v * HH + c0 + j];
        float v0 = acc[0][j] + b, v1 = acc[1][j] + b;
        v0 = v0 > 0.f ? v0 : 0.f;
        v1 = v1 > 0.f ? v1 : 0.f;
        acc[0][j] = v0; acc[1][j] = v1;
        p[j] = v0 + v1;
    }
    #pragma unroll
    for (int i = 0; i < 2; ++i) {
        float4 o = { acc[i][0], acc[i][1], acc[i][2], acc[i][3] };
        *(float4*)&h2[(size_t)(gr0 + r0 + i) * HH + c0] = o;
    }
    *(float4*)&s_p[threadIdx.x >> 5][c0] = *(float4*)p;
    __syncthreads();
    if (threadIdx.x < HH) {
        float a = 0.f;
        #pragma unroll
        for (int q = 0; q < 8; ++q) a += s_p[q][threadIdx.x];
        part[(size_t)blockIdx.x * HH + threadIdx.x] = a;
    }
}

// ---------------------------------------------------------------------------
// Kernel 4: finish summaries, attention MLP, softmax. Single block (512 thr).
// ---------------------------------------------------------------------------
__global__ __launch_bounds__(512) void k_attn(
    const float* __restrict__ part, const float* __restrict__ wa1,
    const float* __restrict__ ba1, const float* __restrict__ wa2,
    const float* __restrict__ ba2, float* __restrict__ attn_out,
    float* __restrict__ attn_ws)
{
    __shared__ float s_sum[VV * HH];
    __shared__ float s_red[256];
    __shared__ float s_score[VV];
    {
        int v = threadIdx.x >> 7, h = threadIdx.x & 127;   // 512 = 4*128
        float a = 0.f;
        #pragma unroll 8
        for (int c = 0; c < CHP; ++c) a += part[(size_t)(v * CHP + c) * HH + h];
        s_sum[v * HH + h] = a * (1.0f / NN);     // mean over N
    }
    __syncthreads();
    if (threadIdx.x < 256) {
        int v = threadIdx.x >> 6, u = threadIdx.x & 63;
        float a = ba1[u];
        for (int k = 0; k < HH; ++k) a += s_sum[v * HH + k] * wa1[k * 64 + u];
        s_red[threadIdx.x] = tanhf(a) * wa2[u];
    }
    __syncthreads();
    if (threadIdx.x < VV) {
        float sc = ba2[0];
        for (int uu = 0; uu < 64; ++uu) sc += s_red[threadIdx.x * 64 + uu];
        s_score[threadIdx.x] = sc;
    }
    __syncthreads();
    if (threadIdx.x == 0) {
        float m = s_score[0];
        for (int i = 1; i < VV; ++i) m = fmaxf(m, s_score[i]);
        float e[VV], den = 0.f;
        for (int i = 0; i < VV; ++i) { e[i] = __expf(s_score[i] - m); den += e[i]; }
        for (int i = 0; i < VV; ++i) {
            float av = e[i] / den;
            attn_out[i] = av;
            attn_ws[i]  = av;
        }
    }
}

// ---------------------------------------------------------------------------
// Kernel 5: fusion MLP. 16 rows/block, 512 threads (2 waves/SIMD at 1 blk/CU).
// ---------------------------------------------------------------------------
__global__ __launch_bounds__(512) void k_fusion(
    const float* __restrict__ h2, const float* __restrict__ attn_ws,
    const float* __restrict__ wf1, const float* __restrict__ bf1,
    const float* __restrict__ wf2, const float* __restrict__ bf2,
    float* __restrict__ fused)
{
    __shared__ float s_in[FR][VV * HH];     // 32 KB
    __shared__ float s_hid[FR][2 * HH];     // 16 KB
    int nbase = blockIdx.x * FR;
    float at[VV];
    #pragma unroll
    for (int v = 0; v < VV; ++v) at[v] = attn_ws[v];

    // stage fusion_in = concat_v(h2[v, n, :] * attn[v]) as float4
    for (int idx = threadIdx.x; idx < FR * VV * HH / 4; idx += 512) {
        int r  = idx >> 7;
        int c4 = idx & 127;
        int v  = c4 >> 5;
        int h4 = c4 & 31;
        const float4* srcr = (const float4*)(h2 + ((size_t)v * NN + nbase + r) * HH);
        float4 x = srcr[h4];
        float s = at[v];
        x.x *= s; x.y *= s; x.z *= s; x.w *= s;
        ((float4*)&s_in[r][0])[c4] = x;
    }
    __syncthreads();

    // GEMM1: hidden[16x256] = relu(s_in[16x512] @ wf1 + bf1), 2x4 per thread
    {
        int r0 = (threadIdx.x >> 6) * 2;       // 0..14
        int c0 = (threadIdx.x & 63) * 4;       // 0..252
        float acc[2][4];
        #pragma unroll
        for (int i = 0; i < 2; ++i)
            #pragma unroll
            for (int j = 0; j < 4; ++j) acc[i][j] = 0.f;
        for (int k = 0; k < VV * HH; k += 4) {
            float4 a[2], w[4];
            #pragma unroll
            for (int i = 0; i < 2; ++i) a[i] = *(const float4*)&s_in[r0 + i][k];
            #pragma unroll
            for (int kk = 0; kk < 4; ++kk)
                w[kk] = *(const float4*)&wf1[(size_t)(k + kk) * (2 * HH) + c0];
            #pragma unroll
            for (int i = 0; i < 2; ++i)
                #pragma unroll
                for (int j = 0; j < 4; ++j) {
                    acc[i][j] += a[i].x * ((const float*)&w[0])[j];
                    acc[i][j] += a[i].y * ((const float*)&w[1])[j];
                    acc[i][j] += a[i].z * ((const float*)&w[2])[j];
                    acc[i][j] += a[i].w * ((const float*)&w[3])[j];
                }
        }
        #pragma unroll
        for (int j = 0; j < 4; ++j) {
            float b = bf1[c0 + j];
            #pragma unroll
            for (int i = 0; i < 2; ++i) {
                float hv = acc[i][j] + b;
                s_hid[r0 + i][c0 + j] = hv > 0.f ? hv : 0.f;
            }
        }
    }
    __syncthreads();

    // GEMM2: fused[16x128] = s_hid[16x256] @ wf2 + bf2, 1x4 per thread
    {
        int r0 = threadIdx.x >> 5;             // 0..15
        int c0 = (threadIdx.x & 31) * 4;       // 0..124
        float acc[4];
        #pragma unroll
        for (int j = 0; j < 4; ++j) acc[j] = 0.f;
        for (int k = 0; k < 2 * HH; k += 4) {
            float4 a = *(const float4*)&s_hid[r0][k];
            float4 w[4];
            #pragma unroll
            for (int kk = 0; kk < 4; ++kk)
                w[kk] = *(const float4*)&wf2[(size_t)(k + kk) * HH + c0];
            #pragma unroll
            for (int j = 0; j < 4; ++j) {
                acc[j] += a.x * ((const float*)&w[0])[j];
                acc[j] += a.y * ((const float*)&w[1])[j];
                acc[j] += a.z * ((const float*)&w[2])[j];
                acc[j] += a.w * ((const float*)&w[3])[j];
            }
        }
        float4 o;
        o.x = acc[0] + bf2[c0 + 0];
        o.y = acc[1] + bf2[c0 + 1];
        o.z = acc[2] + bf2[c0 + 2];
        o.w = acc[3] + bf2[c0 + 3];
        *(float4*)&fused[(size_t)(nbase + r0) * HH + c0] = o;
    }
}

// ---------------------------------------------------------------------------
extern "C" void kernel_launch(void* const* d_in, const int* in_sizes, int n_in,
                              void* d_out, int out_size, void* d_ws, size_t ws_size,
                              hipStream_t stream)
{
    const float* adjs = (const float*)d_in[0];
    const float* w1   = (const float*)d_in[1];
    const float* b1   = (const float*)d_in[2];
    const float* w2   = (const float*)d_in[3];
    const float* b2   = (const float*)d_in[4];
    const float* wa1  = (const float*)d_in[5];
    const float* ba1  = (const float*)d_in[6];
    const float* wa2  = (const float*)d_in[7];
    const float* ba2  = (const float*)d_in[8];
    const float* wf1  = (const float*)d_in[9];
    const float* bf1  = (const float*)d_in[10];
    const float* wf2  = (const float*)d_in[11];
    const float* bf2  = (const float*)d_in[12];

    float* out   = (float*)d_out;
    float* fused = out;                        // [N, 128]
    float* attn  = out + (size_t)NN * HH;      // [V]
    float* h2    = attn + VV;                  // [V, N, H]

    char* w = (char*)d_ws;
    int*   nbr    = (int*)w;    w += (size_t)VV * NN * CAP * sizeof(int);
    int*   cnt    = (int*)w;    w += (size_t)VV * NN * sizeof(int);
    float* dinv   = (float*)w;  w += (size_t)VV * NN * sizeof(float);
    float* h1     = (float*)w;  w += (size_t)VV * NN * HH * sizeof(float);
    float* part   = (float*)w;  w += (size_t)VV * CHP * HH * sizeof(float);
    float* attnws = (float*)w;  w += (size_t)VV * sizeof(float);

    k_build_csr<<<VV * NN / 4, 256, 0, stream>>>(adjs, nbr, cnt, dinv);
    k_spmm1<<<VV * NN / 4, 512, 0, stream>>>(w1, b1, nbr, cnt, dinv, h1);
    k_layer2<<<VV * NN / R2, 256, 0, stream>>>(h1, w2, b2, nbr, cnt, dinv, h2, part);
    k_attn<<<1, 512, 0, stream>>>(part, wa1, ba1, wa2, ba2, attn, attnws);
    k_fusion<<<NN / FR, 512, 0, stream>>>(h2, attnws, wf1, bf1, wf2, bf2, fused);
}